// Round 1
// baseline (546.736 us; speedup 1.0000x reference)
//
#include <hip/hip_runtime.h>
#include <cstddef>

#define B_SZ 1024
#define C_SZ 1000
#define H_SZ 768
#define K_SZ 128

// ---------------------------------------------------------------------------
// Kernel 1: x1 = tanh(relu(-x) @ W^T + bias)
//   x:  [B, H] row-major, W: [H, H] row-major (output h indexes rows of W)
//   x1[b][h] = tanh( sum_j max(-x[b][j],0) * W[h][j] + bias[h] )
// 64x64 tile, BK=16, 256 threads, 4x4 micro-tile per thread.
// LDS tiles stored k-major so the inner loop does float4-friendly reads.
// ---------------------------------------------------------------------------
__global__ __launch_bounds__(256) void gemm_relu_tanh(
    const float* __restrict__ x, const float* __restrict__ W,
    const float* __restrict__ bias, float* __restrict__ x1)
{
    const int TM = 64, TN = 64, BK = 16;
    __shared__ float As[BK][TM];   // As[k][m] = relu(-x[row0+m][k0+k])
    __shared__ float Bs[BK][TN];   // Bs[k][n] = W[col0+n][k0+k]

    const int t    = threadIdx.x;
    const int row0 = blockIdx.y * TM;   // b tile
    const int col0 = blockIdx.x * TN;   // h tile
    const int tx   = t & 15;            // n group (0..15)
    const int ty   = t >> 4;            // m group (0..15)

    // loader mapping: each thread loads one float4 (4 consecutive k) per tile
    const int lk = (t & 3) * 4;         // k offset within tile: 0,4,8,12
    const int lm = t >> 2;              // row within tile: 0..63

    float acc[4][4] = {};

    for (int k0 = 0; k0 < H_SZ; k0 += BK) {
        float4 a4 = *(const float4*)(x + (size_t)(row0 + lm) * H_SZ + k0 + lk);
        As[lk + 0][lm] = fmaxf(-a4.x, 0.f);
        As[lk + 1][lm] = fmaxf(-a4.y, 0.f);
        As[lk + 2][lm] = fmaxf(-a4.z, 0.f);
        As[lk + 3][lm] = fmaxf(-a4.w, 0.f);
        float4 b4 = *(const float4*)(W + (size_t)(col0 + lm) * H_SZ + k0 + lk);
        Bs[lk + 0][lm] = b4.x;
        Bs[lk + 1][lm] = b4.y;
        Bs[lk + 2][lm] = b4.z;
        Bs[lk + 3][lm] = b4.w;
        __syncthreads();

        #pragma unroll
        for (int k = 0; k < BK; ++k) {
            float av[4], bv[4];
            #pragma unroll
            for (int i = 0; i < 4; ++i) av[i] = As[k][ty * 4 + i];
            #pragma unroll
            for (int j = 0; j < 4; ++j) bv[j] = Bs[k][tx * 4 + j];
            #pragma unroll
            for (int i = 0; i < 4; ++i)
                #pragma unroll
                for (int j = 0; j < 4; ++j)
                    acc[i][j] += av[i] * bv[j];
        }
        __syncthreads();
    }

    #pragma unroll
    for (int i = 0; i < 4; ++i) {
        const int m = row0 + ty * 4 + i;
        #pragma unroll
        for (int j = 0; j < 4; ++j) {
            const int n = col0 + tx * 4 + j;
            x1[(size_t)m * H_SZ + n] = tanhf(acc[i][j] + bias[n]);
        }
    }
}

// ---------------------------------------------------------------------------
// Kernel 2: logits[b][k] = sum_h x1[b][h] * CW[y[b]][h][k]
// One block per b. 256 threads = (hg in [0,8)) x (k4 in [0,32) float4 lanes).
// Per h-iteration the block streams 8 consecutive h-rows (4 KB contiguous).
// ---------------------------------------------------------------------------
__global__ __launch_bounds__(256) void gather_dot(
    const float* __restrict__ x1, const int* __restrict__ y,
    const float* __restrict__ cw, float* __restrict__ out)
{
    const int b   = blockIdx.x;
    const int t   = threadIdx.x;
    const int k4  = t & 31;    // float4 index along K (32 * 4 = 128)
    const int hg  = t >> 5;    // h group (0..7)

    __shared__ float sx[H_SZ];
    __shared__ float4 red[256];

    const int cls = y[b];
    const float4* __restrict__ wrow =
        (const float4*)(cw + (size_t)cls * H_SZ * K_SZ);

    for (int i = t; i < H_SZ; i += 256)
        sx[i] = x1[(size_t)b * H_SZ + i];
    __syncthreads();

    float4 acc = {0.f, 0.f, 0.f, 0.f};
    #pragma unroll 4
    for (int h = hg; h < H_SZ; h += 8) {
        const float  xv = sx[h];
        const float4 w  = wrow[h * 32 + k4];
        acc.x += xv * w.x;
        acc.y += xv * w.y;
        acc.z += xv * w.z;
        acc.w += xv * w.w;
    }

    red[t] = acc;
    __syncthreads();
    if (t < 128) {
        float4 o = red[t + 128];
        red[t].x += o.x; red[t].y += o.y; red[t].z += o.z; red[t].w += o.w;
    }
    __syncthreads();
    if (t < 64) {
        float4 o = red[t + 64];
        red[t].x += o.x; red[t].y += o.y; red[t].z += o.z; red[t].w += o.w;
    }
    __syncthreads();
    if (t < 32) {
        float4 r = red[t];
        float4 o = red[t + 32];
        r.x += o.x; r.y += o.y; r.z += o.z; r.w += o.w;
        ((float4*)out)[(size_t)b * 32 + t] = r;
    }
}

extern "C" void kernel_launch(void* const* d_in, const int* in_sizes, int n_in,
                              void* d_out, int out_size, void* d_ws, size_t ws_size,
                              hipStream_t stream) {
    const float* x    = (const float*)d_in[0];   // [B, H]
    const int*   y    = (const int*)  d_in[1];   // [B]
    const float* cw   = (const float*)d_in[2];   // [C, H, K]
    // d_in[3] = class_bias, unused by the reference computation
    const float* Wlin = (const float*)d_in[4];   // [H, H]
    const float* blin = (const float*)d_in[5];   // [H]
    float* out = (float*)d_out;                  // [B, K]
    float* x1  = (float*)d_ws;                   // [B, H] scratch (3 MB)

    dim3 g1(H_SZ / 64, B_SZ / 64);               // 12 x 16 = 192 blocks
    gemm_relu_tanh<<<g1, 256, 0, stream>>>(x, Wlin, blin, x1);
    gather_dot<<<B_SZ, 256, 0, stream>>>(x1, y, cw, out);
}

// Round 2
// 511.444 us; speedup vs baseline: 1.0690x; 1.0690x over previous
//
#include <hip/hip_runtime.h>
#include <hip/hip_bf16.h>
#include <cstddef>

#define B_SZ 1024
#define C_SZ 1000
#define H_SZ 768
#define K_SZ 128

typedef __attribute__((ext_vector_type(8))) short bf16x8;
typedef __attribute__((ext_vector_type(4))) float f32x4;

// ws layout (bytes):
//   [0,        1572864)  : negx bf16 [B][H]   (relu(-x) pre-applied)
//   [1572864,  2752512)  : W    bf16 [H][H]
//   [4194304,  7340032)  : x1   fp32 [B][H]
#define WS_NEGX_OFF 0
#define WS_W_OFF    1572864
#define WS_X1_OFF   4194304

// ---------------------------------------------------------------------------
// Kernel 0: fused convert — negx = bf16(relu(-x)), Wb = bf16(W)
// ---------------------------------------------------------------------------
__global__ __launch_bounds__(256) void convert_pack(
    const float* __restrict__ x, const float* __restrict__ W,
    ushort* __restrict__ negx, ushort* __restrict__ Wb)
{
    const int NX = B_SZ * H_SZ / 4;   // 196608 float4 groups
    const int NW = H_SZ * H_SZ / 4;   // 147456
    int i = blockIdx.x * 256 + threadIdx.x;
    if (i < NX) {
        float4 v = ((const float4*)x)[i];
        union { ushort u[4]; ushort4 v4; } o;
        o.u[0] = __bfloat16_as_ushort(__float2bfloat16(fmaxf(-v.x, 0.f)));
        o.u[1] = __bfloat16_as_ushort(__float2bfloat16(fmaxf(-v.y, 0.f)));
        o.u[2] = __bfloat16_as_ushort(__float2bfloat16(fmaxf(-v.z, 0.f)));
        o.u[3] = __bfloat16_as_ushort(__float2bfloat16(fmaxf(-v.w, 0.f)));
        ((ushort4*)negx)[i] = o.v4;
    } else {
        int j = i - NX;
        if (j < NW) {
            float4 v = ((const float4*)W)[j];
            union { ushort u[4]; ushort4 v4; } o;
            o.u[0] = __bfloat16_as_ushort(__float2bfloat16(v.x));
            o.u[1] = __bfloat16_as_ushort(__float2bfloat16(v.y));
            o.u[2] = __bfloat16_as_ushort(__float2bfloat16(v.z));
            o.u[3] = __bfloat16_as_ushort(__float2bfloat16(v.w));
            ((ushort4*)Wb)[j] = o.v4;
        }
    }
}

// ---------------------------------------------------------------------------
// Kernel 1: x1 = tanh(negx @ W^T + bias) via mfma_f32_16x16x32_bf16
// 64x64 tile, BK=32, 256 threads = 2x2 waves, each wave 2x2 16x16 frags.
// A-frag: lane holds A[m=lane&15][k=(lane>>4)*8 + j] (8 contiguous k of a row)
// B-frag: lane holds B[k][n=lane&15] = W[n=lane&15][k] (same row-of-k load)
// C/D:    col = lane&15, row = (lane>>4)*4 + reg   [verified layout]
// ---------------------------------------------------------------------------
__global__ __launch_bounds__(256) void mfma_gemm_tanh(
    const ushort* __restrict__ A, const ushort* __restrict__ Bw,
    const float* __restrict__ bias, float* __restrict__ x1)
{
    const int LDA = 40;                 // 32 bf16 + 8 pad = 80 B row stride
    __shared__ ushort sA[64 * LDA];
    __shared__ ushort sB[64 * LDA];

    const int t    = threadIdx.x;
    const int wave = t >> 6;            // 0..3
    const int lane = t & 63;
    const int wm   = wave >> 1;         // wave row quadrant (0..1)
    const int wn   = wave & 1;          // wave col quadrant (0..1)
    const int m0   = blockIdx.y * 64;
    const int n0   = blockIdx.x * 64;

    const int lr = t >> 2;              // staging row 0..63
    const int lc = (t & 3) * 8;         // staging col (ushort) 0,8,16,24

    f32x4 acc[2][2] = {};

    const int fr = lane & 15;           // fragment row within 16x16
    const int fk = (lane >> 4) * 8;     // fragment k offset 0,8,16,24

    for (int k0 = 0; k0 < H_SZ; k0 += 32) {
        *(bf16x8*)(&sA[lr * LDA + lc]) =
            *(const bf16x8*)(&A[(size_t)(m0 + lr) * H_SZ + k0 + lc]);
        *(bf16x8*)(&sB[lr * LDA + lc]) =
            *(const bf16x8*)(&Bw[(size_t)(n0 + lr) * H_SZ + k0 + lc]);
        __syncthreads();

        #pragma unroll
        for (int fi = 0; fi < 2; ++fi) {
            bf16x8 af = *(const bf16x8*)(&sA[(wm * 32 + fi * 16 + fr) * LDA + fk]);
            #pragma unroll
            for (int fj = 0; fj < 2; ++fj) {
                bf16x8 bf = *(const bf16x8*)(&sB[(wn * 32 + fj * 16 + fr) * LDA + fk]);
                acc[fi][fj] = __builtin_amdgcn_mfma_f32_16x16x32_bf16(
                    af, bf, acc[fi][fj], 0, 0, 0);
            }
        }
        __syncthreads();
    }

    const int col   = lane & 15;
    const int rbase = (lane >> 4) * 4;
    #pragma unroll
    for (int fi = 0; fi < 2; ++fi) {
        #pragma unroll
        for (int fj = 0; fj < 2; ++fj) {
            const int n  = n0 + wn * 32 + fj * 16 + col;
            const float bv = bias[n];
            #pragma unroll
            for (int r = 0; r < 4; ++r) {
                const int m = m0 + wm * 32 + fi * 16 + rbase + r;
                x1[(size_t)m * H_SZ + n] = tanhf(acc[fi][fj][r] + bv);
            }
        }
    }
}

// ---------------------------------------------------------------------------
// Kernel 2: logits[b][k] = sum_h x1[b][h] * CW[y[b]][h][k]   (unchanged)
// ---------------------------------------------------------------------------
__global__ __launch_bounds__(256) void gather_dot(
    const float* __restrict__ x1, const int* __restrict__ y,
    const float* __restrict__ cw, float* __restrict__ out)
{
    const int b   = blockIdx.x;
    const int t   = threadIdx.x;
    const int k4  = t & 31;
    const int hg  = t >> 5;

    __shared__ float sx[H_SZ];
    __shared__ float4 red[256];

    const int cls = y[b];
    const float4* __restrict__ wrow =
        (const float4*)(cw + (size_t)cls * H_SZ * K_SZ);

    for (int i = t; i < H_SZ; i += 256)
        sx[i] = x1[(size_t)b * H_SZ + i];
    __syncthreads();

    float4 acc = {0.f, 0.f, 0.f, 0.f};
    #pragma unroll 4
    for (int h = hg; h < H_SZ; h += 8) {
        const float  xv = sx[h];
        const float4 w  = wrow[h * 32 + k4];
        acc.x += xv * w.x;
        acc.y += xv * w.y;
        acc.z += xv * w.z;
        acc.w += xv * w.w;
    }

    red[t] = acc;
    __syncthreads();
    if (t < 128) {
        float4 o = red[t + 128];
        red[t].x += o.x; red[t].y += o.y; red[t].z += o.z; red[t].w += o.w;
    }
    __syncthreads();
    if (t < 64) {
        float4 o = red[t + 64];
        red[t].x += o.x; red[t].y += o.y; red[t].z += o.z; red[t].w += o.w;
    }
    __syncthreads();
    if (t < 32) {
        float4 r = red[t];
        float4 o = red[t + 32];
        r.x += o.x; r.y += o.y; r.z += o.z; r.w += o.w;
        ((float4*)out)[(size_t)b * 32 + t] = r;
    }
}

extern "C" void kernel_launch(void* const* d_in, const int* in_sizes, int n_in,
                              void* d_out, int out_size, void* d_ws, size_t ws_size,
                              hipStream_t stream) {
    const float* x    = (const float*)d_in[0];   // [B, H]
    const int*   y    = (const int*)  d_in[1];   // [B]
    const float* cw   = (const float*)d_in[2];   // [C, H, K]
    // d_in[3] = class_bias — unused by the reference math
    const float* Wlin = (const float*)d_in[4];   // [H, H]
    const float* blin = (const float*)d_in[5];   // [H]
    float* out = (float*)d_out;                  // [B, K]

    char* ws = (char*)d_ws;
    ushort* negx = (ushort*)(ws + WS_NEGX_OFF);
    ushort* Wb   = (ushort*)(ws + WS_W_OFF);
    float*  x1   = (float*) (ws + WS_X1_OFF);

    const int total4 = (B_SZ * H_SZ + H_SZ * H_SZ) / 4;
    convert_pack<<<(total4 + 255) / 256, 256, 0, stream>>>(x, Wlin, negx, Wb);

    dim3 g1(H_SZ / 64, B_SZ / 64);               // 12 x 16 = 192 blocks
    mfma_gemm_tanh<<<g1, 256, 0, stream>>>(negx, Wb, blin, x1);

    gather_dot<<<B_SZ, 256, 0, stream>>>(x1, y, cw, out);
}